// Round 1
// baseline (167.736 us; speedup 1.0000x reference)
//
#include <hip/hip_runtime.h>

// B=8, S=4096, E=256, H=4, DK=64. Tokens = B*S = 32768.
// Key insight: the "attention" contracts over heads WITHIN each token
// (scores are (B,S,H,H)) — no cross-token interaction. The op is 4 skinny
// GEMMs (32768x256 @ 256x256) + a per-token 4x4 softmax mix.
// Fully fused: one block = 32 tokens x full N=256; Q/K/V/y live in LDS only.

typedef __bf16 bf16x8 __attribute__((ext_vector_type(8)));
typedef float f32x4 __attribute__((ext_vector_type(4)));

#define LDW 264   // LDS row stride (bf16 elems): 256 + 8 pad (16B-aligned rows, breaks pow2 bank stride)

__device__ __forceinline__ unsigned short f2bf(float f) {
  union { float f; unsigned u; } v; v.f = f;
  unsigned r = v.u + 0x7FFFu + ((v.u >> 16) & 1u);   // RNE
  return (unsigned short)(r >> 16);
}

// Pack Wq|Wk|Wv|Wo (each 256x256 f32) into Wb[1024][256] bf16 in workspace.
// Must re-run every launch: ws is re-poisoned before every timed call.
__global__ void pack_weights(const float* __restrict__ Wq, const float* __restrict__ Wk,
                             const float* __restrict__ Wv, const float* __restrict__ Wo,
                             unsigned short* __restrict__ Wb) {
  int row = blockIdx.x;        // 0..1023
  int col = threadIdx.x;       // 0..255
  const float* src = (row < 256) ? Wq : (row < 512) ? Wk : (row < 768) ? Wv : Wo;
  Wb[row * 256 + col] = f2bf(src[(row & 255) * 256 + col]);
}

__launch_bounds__(256, 2)
__global__ void fused_attn(const float* __restrict__ x, const unsigned short* __restrict__ Wb,
                           const float* __restrict__ bq, const float* __restrict__ bk,
                           const float* __restrict__ bv, const float* __restrict__ bo,
                           float* __restrict__ out) {
  // LDS aliasing: xs holds x-tile, then V (x dead after QKV k-loop);
  // qs holds Q, then Y (Q dead after scores). Total ~52.7 KB -> 2-3 blocks/CU.
  __shared__ unsigned short xs[32 * LDW];
  __shared__ unsigned short qs[32 * LDW];
  __shared__ unsigned short ksh[32 * LDW];
  __shared__ float PL[32 * 16];             // per-token softmax probs (4h x 4g)

  const int tid  = threadIdx.x;
  const int lane = tid & 63;
  const int nw   = tid >> 6;          // wave 0..3 -> 64-col slice (= one head for Q/K/V)
  const int lh   = lane & 15;
  const int lq   = lane >> 4;
  const int n0   = nw * 64;
  const int tok0 = blockIdx.x * 32;

  // ---- stage x tile: 32 tokens x 256 f32 -> bf16 LDS ----
  const float4* xg = (const float4*)(x + (size_t)tok0 * 256);
  #pragma unroll
  for (int t = 0; t < 8; ++t) {
    int f = tid + t * 256;            // float4 index 0..2047
    int row = f >> 6;
    int c4 = (f & 63) * 4;
    float4 v = xg[f];
    ushort4 pk;
    pk.x = f2bf(v.x); pk.y = f2bf(v.y); pk.z = f2bf(v.z); pk.w = f2bf(v.w);
    *(ushort4*)&xs[row * LDW + c4] = pk;
  }
  __syncthreads();

  // ---- QKV GEMM: one K-loop, 3 projections share A-fragments ----
  // A-frag (16x16x32): lane reads 8 consecutive k at row (lane&15), k-quad = lane>>4.
  // B-operand: W is [n][k] row-major = B^T layout; lane reads 8 consecutive k at row n.
  const unsigned short* ap0 = &xs[lh * LDW + lq * 8];
  const unsigned short* ap1 = &xs[(16 + lh) * LDW + lq * 8];
  const unsigned short* bp[3][4];
  #pragma unroll
  for (int p = 0; p < 3; ++p)
    #pragma unroll
    for (int nf = 0; nf < 4; ++nf)
      bp[p][nf] = Wb + (p * 256 + n0 + nf * 16 + lh) * 256 + lq * 8;

  f32x4 acc[3][2][4];
  #pragma unroll
  for (int p = 0; p < 3; ++p)
    #pragma unroll
    for (int mf = 0; mf < 2; ++mf)
      #pragma unroll
      for (int nf = 0; nf < 4; ++nf)
        acc[p][mf][nf] = (f32x4){0.f, 0.f, 0.f, 0.f};

  #pragma unroll
  for (int kk = 0; kk < 8; ++kk) {
    bf16x8 a0 = *(const bf16x8*)(ap0 + kk * 32);
    bf16x8 a1 = *(const bf16x8*)(ap1 + kk * 32);
    #pragma unroll
    for (int p = 0; p < 3; ++p) {
      #pragma unroll
      for (int nf = 0; nf < 4; ++nf) {
        bf16x8 b = *(const bf16x8*)(bp[p][nf] + kk * 32);
        acc[p][0][nf] = __builtin_amdgcn_mfma_f32_16x16x32_bf16(a0, b, acc[p][0][nf], 0, 0, 0);
        acc[p][1][nf] = __builtin_amdgcn_mfma_f32_16x16x32_bf16(a1, b, acc[p][1][nf], 0, 0, 0);
      }
    }
  }

  // ---- write Q,K to LDS (+bias). C/D layout: col=lane&15, row=(lane>>4)*4+reg ----
  #pragma unroll
  for (int nf = 0; nf < 4; ++nf) {
    int col = n0 + nf * 16 + lh;
    float bbq = bq[col], bbk = bk[col];
    #pragma unroll
    for (int mf = 0; mf < 2; ++mf) {
      int r = mf * 16 + lq * 4;
      #pragma unroll
      for (int j = 0; j < 4; ++j) {
        qs[(r + j) * LDW + col]  = f2bf(acc[0][mf][nf][j] + bbq);
        ksh[(r + j) * LDW + col] = f2bf(acc[1][mf][nf][j] + bbk);
      }
    }
  }
  __syncthreads();   // all k-loop reads of xs complete; Q,K visible

  // ---- write V into xs region ----
  #pragma unroll
  for (int nf = 0; nf < 4; ++nf) {
    int col = n0 + nf * 16 + lh;
    float bbv = bv[col];
    #pragma unroll
    for (int mf = 0; mf < 2; ++mf) {
      int r = mf * 16 + lq * 4;
      #pragma unroll
      for (int j = 0; j < 4; ++j)
        xs[(r + j) * LDW + col] = f2bf(acc[2][mf][nf][j] + bbv);
    }
  }
  __syncthreads();

  // ---- per-token head-attention: 8 threads per token ----
  {
    const int m   = tid >> 3;    // token 0..31
    const int sub = tid & 7;
    if (sub < 4) {               // thread owns head h: 4 dots + softmax
      const int h = sub;
      float d0 = 0.f, d1 = 0.f, d2 = 0.f, d3 = 0.f;
      #pragma unroll
      for (int i = 0; i < 8; ++i) {
        bf16x8 qv = *(const bf16x8*)&qs[m * LDW + h * 64 + i * 8];
        bf16x8 k0 = *(const bf16x8*)&ksh[m * LDW +   0 + i * 8];
        bf16x8 k1 = *(const bf16x8*)&ksh[m * LDW +  64 + i * 8];
        bf16x8 k2 = *(const bf16x8*)&ksh[m * LDW + 128 + i * 8];
        bf16x8 k3 = *(const bf16x8*)&ksh[m * LDW + 192 + i * 8];
        #pragma unroll
        for (int j = 0; j < 8; ++j) {
          float qf = (float)qv[j];
          d0 += qf * (float)k0[j];
          d1 += qf * (float)k1[j];
          d2 += qf * (float)k2[j];
          d3 += qf * (float)k3[j];
        }
      }
      d0 *= 0.125f; d1 *= 0.125f; d2 *= 0.125f; d3 *= 0.125f;   // 1/sqrt(64)
      float mx = fmaxf(fmaxf(d0, d1), fmaxf(d2, d3));
      float e0 = expf(d0 - mx), e1 = expf(d1 - mx), e2 = expf(d2 - mx), e3 = expf(d3 - mx);
      float inv = 1.0f / (e0 + e1 + e2 + e3);
      float* pl = &PL[m * 16 + h * 4];
      pl[0] = e0 * inv; pl[1] = e1 * inv; pl[2] = e2 * inv; pl[3] = e3 * inv;
    }
    __syncthreads();             // PL visible; all Q reads done (Y overwrites qs)

    // y[m, h*64+d] = sum_g P[h][g] * v[m, g*64+d]; thread covers 32 cols of one head
    const int h  = sub >> 1;
    const int c0 = (sub & 1) * 32;
    const float p0 = PL[m * 16 + h * 4 + 0];
    const float p1 = PL[m * 16 + h * 4 + 1];
    const float p2 = PL[m * 16 + h * 4 + 2];
    const float p3 = PL[m * 16 + h * 4 + 3];
    #pragma unroll
    for (int dd = 0; dd < 32; dd += 8) {
      int c = c0 + dd;
      bf16x8 v0 = *(const bf16x8*)&xs[m * LDW +   0 + c];
      bf16x8 v1 = *(const bf16x8*)&xs[m * LDW +  64 + c];
      bf16x8 v2 = *(const bf16x8*)&xs[m * LDW + 128 + c];
      bf16x8 v3 = *(const bf16x8*)&xs[m * LDW + 192 + c];
      unsigned short* yd = &qs[m * LDW + h * 64 + c];   // Y reuses Q region
      #pragma unroll
      for (int j = 0; j < 8; ++j) {
        float yv = p0 * (float)v0[j] + p1 * (float)v1[j]
                 + p2 * (float)v2[j] + p3 * (float)v3[j];
        yd[j] = f2bf(yv);
      }
    }
  }
  __syncthreads();

  // ---- output GEMM: out = Y @ Wo.T + bo ----
  const unsigned short* yp0 = &qs[lh * LDW + lq * 8];
  const unsigned short* yp1 = &qs[(16 + lh) * LDW + lq * 8];
  const unsigned short* op[4];
  #pragma unroll
  for (int nf = 0; nf < 4; ++nf)
    op[nf] = Wb + (768 + n0 + nf * 16 + lh) * 256 + lq * 8;

  f32x4 acc2[2][4];
  #pragma unroll
  for (int mf = 0; mf < 2; ++mf)
    #pragma unroll
    for (int nf = 0; nf < 4; ++nf)
      acc2[mf][nf] = (f32x4){0.f, 0.f, 0.f, 0.f};

  #pragma unroll
  for (int kk = 0; kk < 8; ++kk) {
    bf16x8 a0 = *(const bf16x8*)(yp0 + kk * 32);
    bf16x8 a1 = *(const bf16x8*)(yp1 + kk * 32);
    #pragma unroll
    for (int nf = 0; nf < 4; ++nf) {
      bf16x8 b = *(const bf16x8*)(op[nf] + kk * 32);
      acc2[0][nf] = __builtin_amdgcn_mfma_f32_16x16x32_bf16(a0, b, acc2[0][nf], 0, 0, 0);
      acc2[1][nf] = __builtin_amdgcn_mfma_f32_16x16x32_bf16(a1, b, acc2[1][nf], 0, 0, 0);
    }
  }

  #pragma unroll
  for (int nf = 0; nf < 4; ++nf) {
    int col = n0 + nf * 16 + lh;
    float bb = bo[col];
    #pragma unroll
    for (int mf = 0; mf < 2; ++mf) {
      int rbase = tok0 + mf * 16 + lq * 4;
      #pragma unroll
      for (int j = 0; j < 4; ++j)
        out[(rbase + j) * 256 + col] = acc2[mf][nf][j] + bb;
    }
  }
}

extern "C" void kernel_launch(void* const* d_in, const int* in_sizes, int n_in,
                              void* d_out, int out_size, void* d_ws, size_t ws_size,
                              hipStream_t stream) {
  const float* x  = (const float*)d_in[0];
  const float* Wq = (const float*)d_in[1];
  const float* bq = (const float*)d_in[2];
  const float* Wk = (const float*)d_in[3];
  const float* bk = (const float*)d_in[4];
  const float* Wv = (const float*)d_in[5];
  const float* bv = (const float*)d_in[6];
  const float* Wo = (const float*)d_in[7];
  const float* bo = (const float*)d_in[8];
  float* out = (float*)d_out;
  unsigned short* Wb = (unsigned short*)d_ws;   // 1024x256 bf16 = 512 KB

  pack_weights<<<dim3(1024), dim3(256), 0, stream>>>(Wq, Wk, Wv, Wo, Wb);
  fused_attn<<<dim3(1024), dim3(256), 0, stream>>>(x, Wb, bq, bk, bv, bo, out);
}